// Round 13
// baseline (323.643 us; speedup 1.0000x reference)
//
#include <hip/hip_runtime.h>
#include <hip/hip_fp16.h>

// ---------------------------------------------------------------------------
// GNNEncoder: 4x SAGEConv + linear. R12 (on R10/R11 atomic-free CSR build):
//  - mm_dual: A streamed from global via wave-broadcast float4 loads (lanes
//    sharing ty read the same address). As LDS tile dropped: 50KB -> 32KB
//    LDS, 3 -> 5 blocks/CU (R11: 18% occupancy, latency-bound).
//  - gather_lin: final SAGE layer's gather fused with the output linear:
//    per-lane 32-float Wlin register slice, intra-group shfl reduce,
//    coalesced 128B/node store to d_out. mm_lin + hB round-trip eliminated.
//  - single h buffer (gather reads only t,u,adj -> may overwrite its input h).
//  - CSR: hist_pack -> scan_cols -> scan_slices -> bucket_scatter -> csr_fill,
//    zero global atomics (each global atomic costs ~32B memory-side write).
// ---------------------------------------------------------------------------

#define CHUNK 4096          // edges per partition block
#define SLICE_W 512         // nodes per slice (dst>>9)
#define MAXS 128            // max slices (N <= 65536)

// ---- A: pack + per-(slice,block) histogram (LDS atomics only) ----
__global__ __launch_bounds__(256) void hist_pack(
    const int* __restrict__ e32, unsigned* __restrict__ pe,
    int* __restrict__ counts, int E, int S, int Bpad)
{
    __shared__ int h[MAXS];
    const int tid = threadIdx.x, b = blockIdx.x;
    for (int i = tid; i < S; i += 256) h[i] = 0;
    __syncthreads();
    const int lo = b * CHUNK, hi = min(lo + CHUNK, E);
    for (int e = lo + tid; e < hi; e += 256) {
        const int s = e32[e];
        const int d = e32[E + e];
        pe[e] = ((unsigned)s << 16) | (unsigned)d;
        atomicAdd(&h[d >> 9], 1);
    }
    __syncthreads();
    for (int i = tid; i < S; i += 256) counts[i * Bpad + b] = h[i];
}

// ---- B: per-slice exclusive scan over B blocks (B <= 512) ----
__global__ __launch_bounds__(512) void scan_cols(
    int* __restrict__ counts, int* __restrict__ stotal, int B, int Bpad)
{
    __shared__ int sc[512];
    const int s = blockIdx.x, tid = threadIdx.x;
    const int v = (tid < B) ? counts[s * Bpad + tid] : 0;
    sc[tid] = v;
    __syncthreads();
    for (int off = 1; off < 512; off <<= 1) {
        const int a = (tid >= off) ? sc[tid - off] : 0;
        __syncthreads();
        sc[tid] += a;
        __syncthreads();
    }
    if (tid < B) counts[s * Bpad + tid] = sc[tid] - v;   // exclusive
    if (tid == 0) stotal[s] = sc[511];
}

// ---- B2: exclusive scan of slice totals -> slice/bucket/row_ptr bases ----
__global__ __launch_bounds__(MAXS) void scan_slices(
    const int* __restrict__ stotal, int* __restrict__ sbase, int S)
{
    __shared__ int sc[MAXS];
    const int tid = threadIdx.x;
    const int v = (tid < S) ? stotal[tid] : 0;
    sc[tid] = v;
    __syncthreads();
    for (int off = 1; off < MAXS; off <<= 1) {
        const int a = (tid >= off) ? sc[tid - off] : 0;
        __syncthreads();
        sc[tid] += a;
        __syncthreads();
    }
    if (tid < S) sbase[tid] = sc[tid] - v;
}

// ---- C: scatter edges into slice buckets at deterministic positions ----
__global__ __launch_bounds__(256) void bucket_scatter(
    const unsigned* __restrict__ pe, const int* __restrict__ counts,
    const int* __restrict__ sbase, unsigned* __restrict__ bedge,
    int E, int S, int Bpad)
{
    __shared__ int h[MAXS];
    const int tid = threadIdx.x, b = blockIdx.x;
    for (int i = tid; i < S; i += 256) h[i] = 0;
    __syncthreads();
    const int lo = b * CHUNK, hi = min(lo + CHUNK, E);
    for (int e = lo + tid; e < hi; e += 256) {
        const unsigned v = pe[e];
        const int sl = (int)(v & 0xFFFFu) >> 9;
        const int r = atomicAdd(&h[sl], 1);               // LDS rank
        bedge[sbase[sl] + counts[sl * Bpad + b] + r] = v;
    }
}

// ---- D: per-slice CSR finalize: row_ptr, inv, adj (LDS cursors) ----
__global__ __launch_bounds__(1024) void csr_fill(
    const unsigned* __restrict__ bedge, const int* __restrict__ stotal,
    const int* __restrict__ sbase, int* __restrict__ row_ptr,
    float* __restrict__ inv, unsigned short* __restrict__ adj, int N, int E)
{
    __shared__ int cnt[SLICE_W];
    __shared__ int sc[SLICE_W];
    const int s = blockIdx.x, tid = threadIdx.x;
    const int n = stotal[s], base = sbase[s];
    if (tid < SLICE_W) cnt[tid] = 0;
    __syncthreads();
    for (int i = tid; i < n; i += 1024)
        atomicAdd(&cnt[bedge[base + i] & (SLICE_W - 1)], 1);
    __syncthreads();
    if (tid < SLICE_W) sc[tid] = cnt[tid];
    __syncthreads();
    for (int off = 1; off < SLICE_W; off <<= 1) {
        int a = 0;
        if (tid < SLICE_W && tid >= off) a = sc[tid - off];
        __syncthreads();
        if (tid < SLICE_W) sc[tid] += a;
        __syncthreads();
    }
    if (tid < SLICE_W) {
        const int c = cnt[tid];
        const int excl = sc[tid] - c;
        const int node = (s << 9) + tid;
        if (node < N) {
            row_ptr[node] = base + excl;
            inv[node] = 1.0f / (float)(c > 0 ? c : 1);
        }
        cnt[tid] = excl;                   // becomes the cursor
    }
    __syncthreads();
    for (int i = tid; i < n; i += 1024) {
        const unsigned v = bedge[base + i];
        const int p = atomicAdd(&cnt[v & (SLICE_W - 1)], 1);   // LDS cursor
        adj[base + p] = (unsigned short)(v >> 16);
    }
    if (s == 0 && tid == 0) row_ptr[N] = E;
}

// pull aggregation fused with self-term: out = relu(u + inv * sum_j t[adj_j])
// one wave per node: 8 neighbor-groups x 8 dim-lanes, half8 (16B) per lane.
__global__ __launch_bounds__(256) void gather_fused(
    const __half* __restrict__ t, const unsigned short* __restrict__ adj,
    const int* __restrict__ row_ptr, const float* __restrict__ inv,
    const __half* __restrict__ u, float* __restrict__ out, int N)
{
    const int node = (blockIdx.x * 256 + threadIdx.x) >> 6;
    const int lane = threadIdx.x & 63;
    const int grp  = lane >> 3;          // 0..7: neighbor slot in the octet
    const int d0   = (lane & 7) * 8;     // dim offset (8 dims per lane)
    if (node >= N) return;
    const int beg = row_ptr[node], end = row_ptr[node + 1];
    float a[8] = {0.f, 0.f, 0.f, 0.f, 0.f, 0.f, 0.f, 0.f};
    int j = beg + grp;
    for (; j + 8 < end; j += 16) {       // 2x unrolled: j and j+8
        const int n0 = adj[j], n1 = adj[j + 8];
        const float4 p0 = *(const float4*)(t + (size_t)n0 * 64 + d0);
        const float4 p1 = *(const float4*)(t + (size_t)n1 * 64 + d0);
        const __half2* h0 = (const __half2*)&p0;
        const __half2* h1 = (const __half2*)&p1;
        #pragma unroll
        for (int k = 0; k < 4; ++k) {
            float2 f0 = __half22float2(h0[k]);
            float2 f1 = __half22float2(h1[k]);
            a[2 * k]     += f0.x + f1.x;
            a[2 * k + 1] += f0.y + f1.y;
        }
    }
    if (j < end) {
        const float4 p0 = *(const float4*)(t + (size_t)adj[j] * 64 + d0);
        const __half2* h0 = (const __half2*)&p0;
        #pragma unroll
        for (int k = 0; k < 4; ++k) {
            float2 f0 = __half22float2(h0[k]);
            a[2 * k]     += f0.x;
            a[2 * k + 1] += f0.y;
        }
    }
    #pragma unroll
    for (int k = 0; k < 8; ++k) {
        a[k] += __shfl_xor(a[k], 8);
        a[k] += __shfl_xor(a[k], 16);
        a[k] += __shfl_xor(a[k], 32);
    }
    if (grp == 0) {
        const float vi = inv[node];
        const float4 uv = *(const float4*)(u + (size_t)node * 64 + d0);
        const __half2* uh = (const __half2*)&uv;
        float4 o0, o1;
        {
            float2 g0 = __half22float2(uh[0]);
            float2 g1 = __half22float2(uh[1]);
            float2 g2 = __half22float2(uh[2]);
            float2 g3 = __half22float2(uh[3]);
            o0.x = g0.x + a[0] * vi; o0.y = g0.y + a[1] * vi;
            o0.z = g1.x + a[2] * vi; o0.w = g1.y + a[3] * vi;
            o1.x = g2.x + a[4] * vi; o1.y = g2.y + a[5] * vi;
            o1.z = g3.x + a[6] * vi; o1.w = g3.y + a[7] * vi;
        }
        o0.x = fmaxf(o0.x, 0.f); o0.y = fmaxf(o0.y, 0.f);
        o0.z = fmaxf(o0.z, 0.f); o0.w = fmaxf(o0.w, 0.f);
        o1.x = fmaxf(o1.x, 0.f); o1.y = fmaxf(o1.y, 0.f);
        o1.z = fmaxf(o1.z, 0.f); o1.w = fmaxf(o1.w, 0.f);
        *(float4*)(out + (size_t)node * 64 + d0)     = o0;
        *(float4*)(out + (size_t)node * 64 + d0 + 4) = o1;
    }
}

// final layer: out[node,32] = (u + inv*sum_j t[adj_j]) @ Wlin + blin
// gather identical to gather_fused; linear done in-wave:
//  - every lane holds h for its 8 dims (post xor-reduce, replicated x8)
//  - group g (lanes 8g..8g+7) computes output cols 4g..4g+3 from per-lane
//    register slices of Wlin; 3-step intra-group shfl reduce; lane (l&7)==0
//    stores float4 -> 8 groups cover a contiguous 128B row of d_out.
__global__ __launch_bounds__(256) void gather_lin(
    const __half* __restrict__ t, const unsigned short* __restrict__ adj,
    const int* __restrict__ row_ptr, const float* __restrict__ inv,
    const __half* __restrict__ u, const float* __restrict__ Wlin,
    const float* __restrict__ blin, float* __restrict__ out, int N)
{
    const int node = (blockIdx.x * 256 + threadIdx.x) >> 6;
    const int lane = threadIdx.x & 63;
    const int grp  = lane >> 3;
    const int d0   = (lane & 7) * 8;
    if (node >= N) return;
    // per-lane Wlin slice: w[k] = Wlin[(d0+k)*32 + 4*grp .. +3]  (L2-hot, once)
    float4 w[8];
    #pragma unroll
    for (int k = 0; k < 8; ++k)
        w[k] = *(const float4*)&Wlin[(d0 + k) * 32 + 4 * grp];

    const int beg = row_ptr[node], end = row_ptr[node + 1];
    float a[8] = {0.f, 0.f, 0.f, 0.f, 0.f, 0.f, 0.f, 0.f};
    int j = beg + grp;
    for (; j + 8 < end; j += 16) {
        const int n0 = adj[j], n1 = adj[j + 8];
        const float4 p0 = *(const float4*)(t + (size_t)n0 * 64 + d0);
        const float4 p1 = *(const float4*)(t + (size_t)n1 * 64 + d0);
        const __half2* h0 = (const __half2*)&p0;
        const __half2* h1 = (const __half2*)&p1;
        #pragma unroll
        for (int k = 0; k < 4; ++k) {
            float2 f0 = __half22float2(h0[k]);
            float2 f1 = __half22float2(h1[k]);
            a[2 * k]     += f0.x + f1.x;
            a[2 * k + 1] += f0.y + f1.y;
        }
    }
    if (j < end) {
        const float4 p0 = *(const float4*)(t + (size_t)adj[j] * 64 + d0);
        const __half2* h0 = (const __half2*)&p0;
        #pragma unroll
        for (int k = 0; k < 4; ++k) {
            float2 f0 = __half22float2(h0[k]);
            a[2 * k]     += f0.x;
            a[2 * k + 1] += f0.y;
        }
    }
    #pragma unroll
    for (int k = 0; k < 8; ++k) {
        a[k] += __shfl_xor(a[k], 8);
        a[k] += __shfl_xor(a[k], 16);
        a[k] += __shfl_xor(a[k], 32);
    }
    // h for my 8 dims (no relu on layer 2b)
    const float vi = inv[node];
    const float4 uv = *(const float4*)(u + (size_t)node * 64 + d0);
    const __half2* uh = (const __half2*)&uv;
    float h[8];
    {
        float2 g0 = __half22float2(uh[0]);
        float2 g1 = __half22float2(uh[1]);
        float2 g2 = __half22float2(uh[2]);
        float2 g3 = __half22float2(uh[3]);
        h[0] = g0.x + a[0] * vi; h[1] = g0.y + a[1] * vi;
        h[2] = g1.x + a[2] * vi; h[3] = g1.y + a[3] * vi;
        h[4] = g2.x + a[4] * vi; h[5] = g2.y + a[5] * vi;
        h[6] = g3.x + a[6] * vi; h[7] = g3.y + a[7] * vi;
    }
    // partial dot over my 8 dims for my group's 4 cols
    float p0 = 0.f, p1 = 0.f, p2 = 0.f, p3 = 0.f;
    #pragma unroll
    for (int k = 0; k < 8; ++k) {
        p0 += h[k] * w[k].x; p1 += h[k] * w[k].y;
        p2 += h[k] * w[k].z; p3 += h[k] * w[k].w;
    }
    // reduce across the 8 lanes of the group (bits 0,1,2)
    #pragma unroll
    for (int m = 1; m < 8; m <<= 1) {
        p0 += __shfl_xor(p0, m); p1 += __shfl_xor(p1, m);
        p2 += __shfl_xor(p2, m); p3 += __shfl_xor(p3, m);
    }
    if ((lane & 7) == 0) {
        const float4 bv = *(const float4*)&blin[4 * grp];
        float4 o = make_float4(p0 + bv.x, p1 + bv.y, p2 + bv.z, p3 + bv.w);
        *(float4*)&out[(size_t)node * 32 + 4 * grp] = o;
    }
}

// T[M,64](fp16) = A[M,K]@Wl ; U[M,64](fp16) = A[M,K]@Wr + b
// A streamed from global (wave-broadcast float4 loads); only weights in LDS.
template<int K>
__global__ __launch_bounds__(256) void mm_dual(
    const float* __restrict__ A, const float* __restrict__ Wl,
    const float* __restrict__ Wr, const float* __restrict__ bias,
    __half* __restrict__ T, __half* __restrict__ U, int M)
{
    __shared__ float Wls[64 * 64];
    __shared__ float Wrs[64 * 64];
    const int tid  = threadIdx.x;
    const int row0 = blockIdx.x * 64;
    const int tx = tid & 15, ty = tid >> 4;
    float accT[4][4] = {{0.f}}, accU[4][4] = {{0.f}};

    const float* Arow[4];
    bool val[4];
    #pragma unroll
    for (int r = 0; r < 4; ++r) {
        const int gr = row0 + ty * 4 + r;
        val[r] = (gr < M);
        Arow[r] = A + (size_t)(val[r] ? gr : 0) * K;
    }

    for (int kc = 0; kc < K; kc += 64) {
        if (kc) __syncthreads();
        for (int i = tid * 4; i < 64 * 64; i += 1024) {
            *(float4*)&Wls[i] = *(const float4*)&Wl[kc * 64 + i];
            *(float4*)&Wrs[i] = *(const float4*)&Wr[kc * 64 + i];
        }
        __syncthreads();
        for (int kk4 = 0; kk4 < 16; ++kk4) {
            float4 a4[4];
            #pragma unroll
            for (int r = 0; r < 4; ++r)
                a4[r] = val[r] ? *(const float4*)&Arow[r][kc + kk4 * 4]
                               : make_float4(0.f, 0.f, 0.f, 0.f);
            #pragma unroll
            for (int q = 0; q < 4; ++q) {
                const int kk = kk4 * 4 + q;
                float bl[4], br[4];
                #pragma unroll
                for (int c = 0; c < 4; ++c) {
                    bl[c] = Wls[kk * 64 + tx * 4 + c];
                    br[c] = Wrs[kk * 64 + tx * 4 + c];
                }
                #pragma unroll
                for (int r = 0; r < 4; ++r) {
                    const float av = ((const float*)&a4[r])[q];
                    #pragma unroll
                    for (int c = 0; c < 4; ++c) {
                        accT[r][c] += av * bl[c];
                        accU[r][c] += av * br[c];
                    }
                }
            }
        }
    }

    const float4 bv = *(const float4*)&bias[tx * 4];
    #pragma unroll
    for (int r = 0; r < 4; ++r) {
        if (!val[r]) continue;
        const int gr = row0 + ty * 4 + r;
        union { int2 v; __half2 h[2]; } tp;
        tp.h[0] = __floats2half2_rn(accT[r][0], accT[r][1]);
        tp.h[1] = __floats2half2_rn(accT[r][2], accT[r][3]);
        *(int2*)&T[(size_t)gr * 64 + tx * 4] = tp.v;
        union { int2 v; __half2 h[2]; } up;
        up.h[0] = __floats2half2_rn(accU[r][0] + bv.x, accU[r][1] + bv.y);
        up.h[1] = __floats2half2_rn(accU[r][2] + bv.z, accU[r][3] + bv.w);
        *(int2*)&U[(size_t)gr * 64 + tx * 4] = up.v;
    }
}

extern "C" void kernel_launch(void* const* d_in, const int* in_sizes, int n_in,
                              void* d_out, int out_size, void* d_ws, size_t ws_size,
                              hipStream_t stream) {
    const float* x     = (const float*)d_in[0];
    const int*   ei    = (const int*)  d_in[1];
    const float* W1a_l = (const float*)d_in[2];
    const float* b1a   = (const float*)d_in[3];
    const float* W1a_r = (const float*)d_in[4];
    const float* W1b_l = (const float*)d_in[5];
    const float* b1b   = (const float*)d_in[6];
    const float* W1b_r = (const float*)d_in[7];
    const float* W2a_l = (const float*)d_in[8];
    const float* b2a   = (const float*)d_in[9];
    const float* W2a_r = (const float*)d_in[10];
    const float* W2b_l = (const float*)d_in[11];
    const float* b2b   = (const float*)d_in[12];
    const float* W2b_r = (const float*)d_in[13];
    const float* Wlin  = (const float*)d_in[14];
    const float* blin  = (const float*)d_in[15];

    const int N = in_sizes[0] / 128;
    const int E = in_sizes[1] / 2;
    const int S = (N + SLICE_W - 1) / SLICE_W;      // 98 slices @ N=50k
    const int B = (E + CHUNK - 1) / CHUNK;          // 391 chunks @ E=1.6M
    const int Bpad = (B + 15) & ~15;                // 400

    size_t o = 0;
    auto take = [&](size_t bytes) -> void* {
        void* p = (char*)d_ws + o;
        o += (bytes + 255) & ~(size_t)255;
        return p;
    };
    unsigned*       pe      = (unsigned*)take((size_t)E * 4);
    unsigned*       bedge   = (unsigned*)take((size_t)E * 4);
    int*            counts  = (int*)   take((size_t)S * Bpad * 4);
    int*            stotal  = (int*)   take((size_t)S * 4);
    int*            sbase   = (int*)   take((size_t)S * 4);
    int*            row_ptr = (int*)   take((size_t)(N + 1) * 4);
    float*          inv     = (float*) take((size_t)N * 4);
    unsigned short* adj     = (unsigned short*)take((size_t)E * 2);
    __half*         t       = (__half*)take((size_t)N * 64 * 2);
    __half*         u       = (__half*)take((size_t)N * 64 * 2);
    float*          h       = (float*) take((size_t)N * 64 * 4);
    (void)ws_size; (void)n_in; (void)out_size;

    const int mb = (N + 63) / 64;                 // mm blocks
    const int gb = (N * 64 + 255) / 256;          // gather blocks (wave/node)

    // ---- build CSR: zero global atomics ----
    hist_pack<<<B, 256, 0, stream>>>(ei, pe, counts, E, S, Bpad);
    scan_cols<<<S, 512, 0, stream>>>(counts, stotal, B, Bpad);
    scan_slices<<<1, MAXS, 0, stream>>>(stotal, sbase, S);
    bucket_scatter<<<B, 256, 0, stream>>>(pe, counts, sbase, bedge, E, S, Bpad);
    csr_fill<<<S, 1024, 0, stream>>>(bedge, stotal, sbase, row_ptr, inv, adj, N, E);

    // ---- layer 1a: x[*,128] -> h, relu ----
    mm_dual<128><<<mb, 256, 0, stream>>>(x, W1a_l, W1a_r, b1a, t, u, N);
    gather_fused<<<gb, 256, 0, stream>>>(t, adj, row_ptr, inv, u, h, N);
    // ---- layer 1b: h -> h, relu ----
    mm_dual<64><<<mb, 256, 0, stream>>>(h, W1b_l, W1b_r, b1b, t, u, N);
    gather_fused<<<gb, 256, 0, stream>>>(t, adj, row_ptr, inv, u, h, N);
    // ---- layer 2a: h -> h, relu ----
    mm_dual<64><<<mb, 256, 0, stream>>>(h, W2a_l, W2a_r, b2a, t, u, N);
    gather_fused<<<gb, 256, 0, stream>>>(t, adj, row_ptr, inv, u, h, N);
    // ---- layer 2b + final linear fused: h -> d_out ----
    mm_dual<64><<<mb, 256, 0, stream>>>(h, W2b_l, W2b_r, b2b, t, u, N);
    gather_lin<<<gb, 256, 0, stream>>>(t, adj, row_ptr, inv, u, Wlin, blin,
                                       (float*)d_out, N);
}

// Round 14
// 264.357 us; speedup vs baseline: 1.2243x; 1.2243x over previous
//
#include <hip/hip_runtime.h>
#include <hip/hip_fp16.h>

// ---------------------------------------------------------------------------
// GNNEncoder: 4x SAGEConv + linear. R13 = R11 structure + mm_dual K-chunk 32:
//  - REVERTED R12's A-streaming (dependent broadcast loads lost to LDS
//    staging) and gather_lin fusion (per-wave Wlin reload = 400MB L1 churn,
//    70us vs 35us for gather+mm_lin).
//  - mm_dual: K-chunk 32 -> LDS 50KB -> 25.6KB -> 3 -> 6 blocks/CU.
//    (R10 counters: 18% occupancy, VALUBusy 29% = latency-bound.)
//  - CSR build: hist_pack -> scan_cols -> scan_slices -> bucket_scatter ->
//    csr_fill(1024t). Zero global atomics (~32B memory-side write each).
//  - t,u fp16 (fp32 accumulate); gather: wave/node, 8 nbr-groups x 8 dims.
// ---------------------------------------------------------------------------

#define CHUNK 4096          // edges per partition block
#define SLICE_W 512         // nodes per slice (dst>>9)
#define MAXS 128            // max slices (N <= 65536)

// ---- A: pack + per-(slice,block) histogram (LDS atomics only) ----
__global__ __launch_bounds__(256) void hist_pack(
    const int* __restrict__ e32, unsigned* __restrict__ pe,
    int* __restrict__ counts, int E, int S, int Bpad)
{
    __shared__ int h[MAXS];
    const int tid = threadIdx.x, b = blockIdx.x;
    for (int i = tid; i < S; i += 256) h[i] = 0;
    __syncthreads();
    const int lo = b * CHUNK, hi = min(lo + CHUNK, E);
    for (int e = lo + tid; e < hi; e += 256) {
        const int s = e32[e];
        const int d = e32[E + e];
        pe[e] = ((unsigned)s << 16) | (unsigned)d;
        atomicAdd(&h[d >> 9], 1);
    }
    __syncthreads();
    for (int i = tid; i < S; i += 256) counts[i * Bpad + b] = h[i];
}

// ---- B: per-slice exclusive scan over B blocks (B <= 512) ----
__global__ __launch_bounds__(512) void scan_cols(
    int* __restrict__ counts, int* __restrict__ stotal, int B, int Bpad)
{
    __shared__ int sc[512];
    const int s = blockIdx.x, tid = threadIdx.x;
    const int v = (tid < B) ? counts[s * Bpad + tid] : 0;
    sc[tid] = v;
    __syncthreads();
    for (int off = 1; off < 512; off <<= 1) {
        const int a = (tid >= off) ? sc[tid - off] : 0;
        __syncthreads();
        sc[tid] += a;
        __syncthreads();
    }
    if (tid < B) counts[s * Bpad + tid] = sc[tid] - v;   // exclusive
    if (tid == 0) stotal[s] = sc[511];
}

// ---- B2: exclusive scan of slice totals -> slice/bucket/row_ptr bases ----
__global__ __launch_bounds__(MAXS) void scan_slices(
    const int* __restrict__ stotal, int* __restrict__ sbase, int S)
{
    __shared__ int sc[MAXS];
    const int tid = threadIdx.x;
    const int v = (tid < S) ? stotal[tid] : 0;
    sc[tid] = v;
    __syncthreads();
    for (int off = 1; off < MAXS; off <<= 1) {
        const int a = (tid >= off) ? sc[tid - off] : 0;
        __syncthreads();
        sc[tid] += a;
        __syncthreads();
    }
    if (tid < S) sbase[tid] = sc[tid] - v;
}

// ---- C: scatter edges into slice buckets at deterministic positions ----
__global__ __launch_bounds__(256) void bucket_scatter(
    const unsigned* __restrict__ pe, const int* __restrict__ counts,
    const int* __restrict__ sbase, unsigned* __restrict__ bedge,
    int E, int S, int Bpad)
{
    __shared__ int h[MAXS];
    const int tid = threadIdx.x, b = blockIdx.x;
    for (int i = tid; i < S; i += 256) h[i] = 0;
    __syncthreads();
    const int lo = b * CHUNK, hi = min(lo + CHUNK, E);
    for (int e = lo + tid; e < hi; e += 256) {
        const unsigned v = pe[e];
        const int sl = (int)(v & 0xFFFFu) >> 9;
        const int r = atomicAdd(&h[sl], 1);               // LDS rank
        bedge[sbase[sl] + counts[sl * Bpad + b] + r] = v;
    }
}

// ---- D: per-slice CSR finalize: row_ptr, inv, adj (LDS cursors) ----
__global__ __launch_bounds__(1024) void csr_fill(
    const unsigned* __restrict__ bedge, const int* __restrict__ stotal,
    const int* __restrict__ sbase, int* __restrict__ row_ptr,
    float* __restrict__ inv, unsigned short* __restrict__ adj, int N, int E)
{
    __shared__ int cnt[SLICE_W];
    __shared__ int sc[SLICE_W];
    const int s = blockIdx.x, tid = threadIdx.x;
    const int n = stotal[s], base = sbase[s];
    if (tid < SLICE_W) cnt[tid] = 0;
    __syncthreads();
    for (int i = tid; i < n; i += 1024)
        atomicAdd(&cnt[bedge[base + i] & (SLICE_W - 1)], 1);
    __syncthreads();
    if (tid < SLICE_W) sc[tid] = cnt[tid];
    __syncthreads();
    for (int off = 1; off < SLICE_W; off <<= 1) {
        int a = 0;
        if (tid < SLICE_W && tid >= off) a = sc[tid - off];
        __syncthreads();
        if (tid < SLICE_W) sc[tid] += a;
        __syncthreads();
    }
    if (tid < SLICE_W) {
        const int c = cnt[tid];
        const int excl = sc[tid] - c;
        const int node = (s << 9) + tid;
        if (node < N) {
            row_ptr[node] = base + excl;
            inv[node] = 1.0f / (float)(c > 0 ? c : 1);
        }
        cnt[tid] = excl;                   // becomes the cursor
    }
    __syncthreads();
    for (int i = tid; i < n; i += 1024) {
        const unsigned v = bedge[base + i];
        const int p = atomicAdd(&cnt[v & (SLICE_W - 1)], 1);   // LDS cursor
        adj[base + p] = (unsigned short)(v >> 16);
    }
    if (s == 0 && tid == 0) row_ptr[N] = E;
}

// pull aggregation fused with self-term: out = (relu)(u + inv * sum_j t[adj_j])
// one wave per node: 8 neighbor-groups x 8 dim-lanes, half8 (16B) per lane.
template<bool RELU>
__global__ __launch_bounds__(256) void gather_fused(
    const __half* __restrict__ t, const unsigned short* __restrict__ adj,
    const int* __restrict__ row_ptr, const float* __restrict__ inv,
    const __half* __restrict__ u, float* __restrict__ out, int N)
{
    const int node = (blockIdx.x * 256 + threadIdx.x) >> 6;
    const int lane = threadIdx.x & 63;
    const int grp  = lane >> 3;          // 0..7: neighbor slot in the octet
    const int d0   = (lane & 7) * 8;     // dim offset (8 dims per lane)
    if (node >= N) return;
    const int beg = row_ptr[node], end = row_ptr[node + 1];
    float a[8] = {0.f, 0.f, 0.f, 0.f, 0.f, 0.f, 0.f, 0.f};
    int j = beg + grp;
    for (; j + 8 < end; j += 16) {       // 2x unrolled: j and j+8
        const int n0 = adj[j], n1 = adj[j + 8];
        const float4 p0 = *(const float4*)(t + (size_t)n0 * 64 + d0);
        const float4 p1 = *(const float4*)(t + (size_t)n1 * 64 + d0);
        const __half2* h0 = (const __half2*)&p0;
        const __half2* h1 = (const __half2*)&p1;
        #pragma unroll
        for (int k = 0; k < 4; ++k) {
            float2 f0 = __half22float2(h0[k]);
            float2 f1 = __half22float2(h1[k]);
            a[2 * k]     += f0.x + f1.x;
            a[2 * k + 1] += f0.y + f1.y;
        }
    }
    if (j < end) {
        const float4 p0 = *(const float4*)(t + (size_t)adj[j] * 64 + d0);
        const __half2* h0 = (const __half2*)&p0;
        #pragma unroll
        for (int k = 0; k < 4; ++k) {
            float2 f0 = __half22float2(h0[k]);
            a[2 * k]     += f0.x;
            a[2 * k + 1] += f0.y;
        }
    }
    // reduce across the 8 groups (lane bits 3,4,5)
    #pragma unroll
    for (int k = 0; k < 8; ++k) {
        a[k] += __shfl_xor(a[k], 8);
        a[k] += __shfl_xor(a[k], 16);
        a[k] += __shfl_xor(a[k], 32);
    }
    if (grp == 0) {
        const float vi = inv[node];
        const float4 uv = *(const float4*)(u + (size_t)node * 64 + d0);
        const __half2* uh = (const __half2*)&uv;
        float4 o0, o1;
        {
            float2 g0 = __half22float2(uh[0]);
            float2 g1 = __half22float2(uh[1]);
            float2 g2 = __half22float2(uh[2]);
            float2 g3 = __half22float2(uh[3]);
            o0.x = g0.x + a[0] * vi; o0.y = g0.y + a[1] * vi;
            o0.z = g1.x + a[2] * vi; o0.w = g1.y + a[3] * vi;
            o1.x = g2.x + a[4] * vi; o1.y = g2.y + a[5] * vi;
            o1.z = g3.x + a[6] * vi; o1.w = g3.y + a[7] * vi;
        }
        if (RELU) {
            o0.x = fmaxf(o0.x, 0.f); o0.y = fmaxf(o0.y, 0.f);
            o0.z = fmaxf(o0.z, 0.f); o0.w = fmaxf(o0.w, 0.f);
            o1.x = fmaxf(o1.x, 0.f); o1.y = fmaxf(o1.y, 0.f);
            o1.z = fmaxf(o1.z, 0.f); o1.w = fmaxf(o1.w, 0.f);
        }
        *(float4*)(out + (size_t)node * 64 + d0)     = o0;
        *(float4*)(out + (size_t)node * 64 + d0 + 4) = o1;
    }
}

// T[M,64](fp16) = A[M,K]@Wl ; U[M,64](fp16) = A[M,K]@Wr + b
// K-chunk 32: LDS = As[64][36] + Wls[32*64] + Wrs[32*64] = 25.6KB -> 6 blk/CU
template<int K>
__global__ __launch_bounds__(256) void mm_dual(
    const float* __restrict__ A, const float* __restrict__ Wl,
    const float* __restrict__ Wr, const float* __restrict__ bias,
    __half* __restrict__ T, __half* __restrict__ U, int M)
{
    __shared__ float As[64][36];
    __shared__ float Wls[32 * 64];
    __shared__ float Wrs[32 * 64];
    const int tid  = threadIdx.x;
    const int row0 = blockIdx.x * 64;
    const int tx = tid & 15, ty = tid >> 4;
    float accT[4][4] = {{0.f}}, accU[4][4] = {{0.f}};

    for (int kc = 0; kc < K; kc += 32) {
        if (kc) __syncthreads();
        for (int i = tid * 4; i < 64 * 32; i += 1024) {
            int r = i >> 5, c = i & 31;
            int gr = row0 + r;
            float4 v = make_float4(0.f, 0.f, 0.f, 0.f);
            if (gr < M) v = *(const float4*)&A[(size_t)gr * K + kc + c];
            *(float4*)&As[r][c] = v;
        }
        for (int i = tid * 4; i < 32 * 64; i += 1024) {
            *(float4*)&Wls[i] = *(const float4*)&Wl[kc * 64 + i];
            *(float4*)&Wrs[i] = *(const float4*)&Wr[kc * 64 + i];
        }
        __syncthreads();
        #pragma unroll 4
        for (int kk = 0; kk < 32; ++kk) {
            float a[4];
            #pragma unroll
            for (int r = 0; r < 4; ++r) a[r] = As[ty * 4 + r][kk];
            float bl[4], br[4];
            #pragma unroll
            for (int c = 0; c < 4; ++c) {
                bl[c] = Wls[kk * 64 + tx * 4 + c];
                br[c] = Wrs[kk * 64 + tx * 4 + c];
            }
            #pragma unroll
            for (int r = 0; r < 4; ++r)
                #pragma unroll
                for (int c = 0; c < 4; ++c) {
                    accT[r][c] += a[r] * bl[c];
                    accU[r][c] += a[r] * br[c];
                }
        }
    }

    const float4 bv = *(const float4*)&bias[tx * 4];
    #pragma unroll
    for (int r = 0; r < 4; ++r) {
        int gr = row0 + ty * 4 + r;
        if (gr >= M) continue;
        union { int2 v; __half2 h[2]; } tp;
        tp.h[0] = __floats2half2_rn(accT[r][0], accT[r][1]);
        tp.h[1] = __floats2half2_rn(accT[r][2], accT[r][3]);
        *(int2*)&T[(size_t)gr * 64 + tx * 4] = tp.v;
        union { int2 v; __half2 h[2]; } up;
        up.h[0] = __floats2half2_rn(accU[r][0] + bv.x, accU[r][1] + bv.y);
        up.h[1] = __floats2half2_rn(accU[r][2] + bv.z, accU[r][3] + bv.w);
        *(int2*)&U[(size_t)gr * 64 + tx * 4] = up.v;
    }
}

// final linear: C[M,32] = A[M,64]@W + b
__global__ __launch_bounds__(256) void mm_lin(
    const float* __restrict__ A, const float* __restrict__ W,
    const float* __restrict__ bias, float* __restrict__ C, int M)
{
    __shared__ float As[64][68];
    __shared__ float Ws[64 * 32];
    const int tid  = threadIdx.x;
    const int row0 = blockIdx.x * 64;

    for (int i = tid * 4; i < 64 * 32; i += 1024) {
        *(float4*)&Ws[i] = *(const float4*)&W[i];
    }
    for (int i = tid * 4; i < 64 * 64; i += 1024) {
        int r = i >> 6, c = i & 63;
        int gr = row0 + r;
        float4 v = make_float4(0.f, 0.f, 0.f, 0.f);
        if (gr < M) v = *(const float4*)&A[(size_t)gr * 64 + c];
        *(float4*)&As[r][c] = v;
    }
    __syncthreads();

    const int tx = tid & 15, ty = tid >> 4;
    float acc[4][2] = {{0.f}};
    #pragma unroll 4
    for (int kk = 0; kk < 64; ++kk) {
        float a[4];
        #pragma unroll
        for (int r = 0; r < 4; ++r) a[r] = As[ty * 4 + r][kk];
        float b0 = Ws[kk * 32 + tx * 2];
        float b1 = Ws[kk * 32 + tx * 2 + 1];
        #pragma unroll
        for (int r = 0; r < 4; ++r) {
            acc[r][0] += a[r] * b0;
            acc[r][1] += a[r] * b1;
        }
    }
    #pragma unroll
    for (int r = 0; r < 4; ++r) {
        int gr = row0 + ty * 4 + r;
        if (gr >= M) continue;
        float2 o = make_float2(acc[r][0] + bias[tx * 2],
                               acc[r][1] + bias[tx * 2 + 1]);
        *(float2*)&C[(size_t)gr * 32 + tx * 2] = o;
    }
}

extern "C" void kernel_launch(void* const* d_in, const int* in_sizes, int n_in,
                              void* d_out, int out_size, void* d_ws, size_t ws_size,
                              hipStream_t stream) {
    const float* x     = (const float*)d_in[0];
    const int*   ei    = (const int*)  d_in[1];
    const float* W1a_l = (const float*)d_in[2];
    const float* b1a   = (const float*)d_in[3];
    const float* W1a_r = (const float*)d_in[4];
    const float* W1b_l = (const float*)d_in[5];
    const float* b1b   = (const float*)d_in[6];
    const float* W1b_r = (const float*)d_in[7];
    const float* W2a_l = (const float*)d_in[8];
    const float* b2a   = (const float*)d_in[9];
    const float* W2a_r = (const float*)d_in[10];
    const float* W2b_l = (const float*)d_in[11];
    const float* b2b   = (const float*)d_in[12];
    const float* W2b_r = (const float*)d_in[13];
    const float* Wlin  = (const float*)d_in[14];
    const float* blin  = (const float*)d_in[15];

    const int N = in_sizes[0] / 128;
    const int E = in_sizes[1] / 2;
    const int S = (N + SLICE_W - 1) / SLICE_W;      // 98 slices @ N=50k
    const int B = (E + CHUNK - 1) / CHUNK;          // 391 chunks @ E=1.6M
    const int Bpad = (B + 15) & ~15;                // 400

    size_t o = 0;
    auto take = [&](size_t bytes) -> void* {
        void* p = (char*)d_ws + o;
        o += (bytes + 255) & ~(size_t)255;
        return p;
    };
    unsigned*       pe      = (unsigned*)take((size_t)E * 4);
    unsigned*       bedge   = (unsigned*)take((size_t)E * 4);
    int*            counts  = (int*)   take((size_t)S * Bpad * 4);
    int*            stotal  = (int*)   take((size_t)S * 4);
    int*            sbase   = (int*)   take((size_t)S * 4);
    int*            row_ptr = (int*)   take((size_t)(N + 1) * 4);
    float*          inv     = (float*) take((size_t)N * 4);
    unsigned short* adj     = (unsigned short*)take((size_t)E * 2);
    __half*         t       = (__half*)take((size_t)N * 64 * 2);
    __half*         u       = (__half*)take((size_t)N * 64 * 2);
    float*          hA      = (float*) take((size_t)N * 64 * 4);
    float*          hB      = (float*) take((size_t)N * 64 * 4);
    (void)ws_size; (void)n_in; (void)out_size;

    const int mb = (N + 63) / 64;                 // mm blocks
    const int gb = (N * 64 + 255) / 256;          // gather blocks (wave/node)

    // ---- build CSR: zero global atomics ----
    hist_pack<<<B, 256, 0, stream>>>(ei, pe, counts, E, S, Bpad);
    scan_cols<<<S, 512, 0, stream>>>(counts, stotal, B, Bpad);
    scan_slices<<<1, MAXS, 0, stream>>>(stotal, sbase, S);
    bucket_scatter<<<B, 256, 0, stream>>>(pe, counts, sbase, bedge, E, S, Bpad);
    csr_fill<<<S, 1024, 0, stream>>>(bedge, stotal, sbase, row_ptr, inv, adj, N, E);

    // ---- layer 1a: x[*,128] -> hA, relu ----
    mm_dual<128><<<mb, 256, 0, stream>>>(x, W1a_l, W1a_r, b1a, t, u, N);
    gather_fused<true><<<gb, 256, 0, stream>>>(t, adj, row_ptr, inv, u, hA, N);
    // ---- layer 1b: hA -> hB, relu ----
    mm_dual<64><<<mb, 256, 0, stream>>>(hA, W1b_l, W1b_r, b1b, t, u, N);
    gather_fused<true><<<gb, 256, 0, stream>>>(t, adj, row_ptr, inv, u, hB, N);
    // ---- layer 2a: hB -> hA, relu ----
    mm_dual<64><<<mb, 256, 0, stream>>>(hB, W2a_l, W2a_r, b2a, t, u, N);
    gather_fused<true><<<gb, 256, 0, stream>>>(t, adj, row_ptr, inv, u, hA, N);
    // ---- layer 2b: hA -> hB, no relu ----
    mm_dual<64><<<mb, 256, 0, stream>>>(hA, W2b_l, W2b_r, b2b, t, u, N);
    gather_fused<false><<<gb, 256, 0, stream>>>(t, adj, row_ptr, inv, u, hB, N);
    // ---- final linear ----
    mm_lin<<<mb, 256, 0, stream>>>(hB, Wlin, blin, (float*)d_out, N);
}